// Round 9
// baseline (401.011 us; speedup 1.0000x reference)
//
#include <hip/hip_runtime.h>

constexpr int HW = 1024 * 1024;
constexpr int NB = 16;
constexpr float EPS = 1e-6f;
constexpr int BLOCKS_PER_BATCH = 128;  // 2048 blocks total -> 8 blocks/CU
constexpr int THREADS = 256;
constexpr int NVEC    = HW / 4;                      // 262144 vec4 per batch
constexpr int TPB     = BLOCKS_PER_BATCH * THREADS;  // 32768 threads per batch
constexpr int U       = NVEC / TPB;                  // 8 windows per thread (exact)
constexpr int NBLK    = NB * BLOCKS_PER_BATCH;       // 2048

typedef float f32x4 __attribute__((ext_vector_type(4)));
typedef int   i32x4 __attribute__((ext_vector_type(4)));

// Fused: per-block partials (R6's best body: nt loads, depth-2 pipeline),
// then last-block-done reduction — no second kernel launch.
__global__ __launch_bounds__(THREADS, 8) void dice_fused(
        const float* __restrict__ logits,
        const int*   __restrict__ labels,
        float*       __restrict__ wsf,    // 2048 * 4 floats of partials
        unsigned int* __restrict__ cnt,   // ticket counter (pre-zeroed)
        float*       __restrict__ out) {
    const int b   = blockIdx.x >> 7;         // / BLOCKS_PER_BATCH
    const int blk = blockIdx.x & 127;        // % BLOCKS_PER_BATCH

    const f32x4* __restrict__ L0 = reinterpret_cast<const f32x4*>(logits + (size_t)b * 2 * HW);
    const f32x4* __restrict__ L1 = reinterpret_cast<const f32x4*>(logits + (size_t)b * 2 * HW + HW);
    const i32x4* __restrict__ LB = reinterpret_cast<const i32x4*>(labels + (size_t)b * HW);

    const int base = blk * THREADS + threadIdx.x;   // [0, 32768)

    f32x4 a[2], c[2];
    i32x4 t[2];
    a[0] = __builtin_nontemporal_load(&L0[base]);
    c[0] = __builtin_nontemporal_load(&L1[base]);
    t[0] = __builtin_nontemporal_load(&LB[base]);
    a[1] = __builtin_nontemporal_load(&L0[base + TPB]);
    c[1] = __builtin_nontemporal_load(&L1[base + TPB]);
    t[1] = __builtin_nontemporal_load(&LB[base + TPB]);

    float sp = 0.f, spp = 0.f, st = 0.f, stp = 0.f;

    #pragma unroll
    for (int u = 0; u < U; ++u) {
        const int cur = u & 1;
        f32x4 an, cn;
        i32x4 tn;
        const bool pf = (u + 2 < U);
        if (pf) {
            const int i = base + (u + 2) * TPB;
            an = __builtin_nontemporal_load(&L0[i]);
            cn = __builtin_nontemporal_load(&L1[i]);
            tn = __builtin_nontemporal_load(&LB[i]);
        }
        #pragma unroll
        for (int k = 0; k < 4; ++k) {
            const float p  = 1.f / (1.f + __expf(a[cur][k] - c[cur][k]));
            const float tf = (float)t[cur][k];
            sp += p; spp = fmaf(p, p, spp); st += tf; stp = fmaf(tf, p, stp);
        }
        if (pf) { a[cur] = an; c[cur] = cn; t[cur] = tn; }
    }

    // wave-64 shuffle reduction
    #pragma unroll
    for (int off = 32; off > 0; off >>= 1) {
        sp  += __shfl_down(sp,  off);
        spp += __shfl_down(spp, off);
        st  += __shfl_down(st,  off);
        stp += __shfl_down(stp, off);
    }

    __shared__ float red[4][4];   // [wave][component]
    const int wave = threadIdx.x >> 6;
    const int lane = threadIdx.x & 63;
    if (lane == 0) {
        red[wave][0] = sp; red[wave][1] = spp; red[wave][2] = st; red[wave][3] = stp;
    }
    __syncthreads();

    __shared__ bool s_last;
    if (threadIdx.x == 0) {
        const int o = blockIdx.x * 4;
        wsf[o + 0] = red[0][0] + red[1][0] + red[2][0] + red[3][0];
        wsf[o + 1] = red[0][1] + red[1][1] + red[2][1] + red[3][1];
        wsf[o + 2] = red[0][2] + red[1][2] + red[2][2] + red[3][2];
        wsf[o + 3] = red[0][3] + red[1][3] + red[2][3] + red[3][3];
        __threadfence();   // make partials visible at agent scope
        const unsigned int ticket =
            __hip_atomic_fetch_add(cnt, 1u, __ATOMIC_ACQ_REL, __HIP_MEMORY_SCOPE_AGENT);
        s_last = (ticket == (unsigned int)(NBLK - 1));
    }
    __syncthreads();
    if (!s_last) return;

    // ---- Last block: fold all 2048 partials -> scalar loss ----
    // Thread t sums entries [t*8, t*8+8) — all within batch t/16.
    float4 acc = {0.f, 0.f, 0.f, 0.f};
    #pragma unroll
    for (int e = 0; e < 8; ++e) {
        const int idx = (threadIdx.x * 8 + e) * 4;
        acc.x += __hip_atomic_load(&wsf[idx + 0], __ATOMIC_RELAXED, __HIP_MEMORY_SCOPE_AGENT);
        acc.y += __hip_atomic_load(&wsf[idx + 1], __ATOMIC_RELAXED, __HIP_MEMORY_SCOPE_AGENT);
        acc.z += __hip_atomic_load(&wsf[idx + 2], __ATOMIC_RELAXED, __HIP_MEMORY_SCOPE_AGENT);
        acc.w += __hip_atomic_load(&wsf[idx + 3], __ATOMIC_RELAXED, __HIP_MEMORY_SCOPE_AGENT);
    }

    __shared__ float sums[THREADS][4];
    sums[threadIdx.x][0] = acc.x;
    sums[threadIdx.x][1] = acc.y;
    sums[threadIdx.x][2] = acc.z;
    sums[threadIdx.x][3] = acc.w;
    __syncthreads();

    __shared__ float terms[NB];
    if (threadIdx.x < NB) {            // thread tb folds batch tb's 16 sub-sums
        const int tb = threadIdx.x;
        float Sp = 0.f, Spp = 0.f, St = 0.f, Stp = 0.f;
        #pragma unroll
        for (int j = 0; j < 16; ++j) {
            Sp  += sums[tb * 16 + j][0];
            Spp += sums[tb * 16 + j][1];
            St  += sums[tb * 16 + j][2];
            Stp += sums[tb * 16 + j][3];
        }
        const float N = (float)HW;
        const float num1 = 2.f * Stp;
        const float den1 = Spp + St;
        const float num0 = 2.f * (N - St - Sp + Stp);
        const float den0 = (N - 2.f * Sp + Spp) + (N - St);
        terms[tb] = num0 / (den0 + EPS) + num1 / (den1 + EPS);
    }
    __syncthreads();
    if (threadIdx.x == 0) {
        float s = 0.f;
        #pragma unroll
        for (int i = 0; i < NB; ++i) s += terms[i];
        out[0] = 1.f - s / 32.f;
    }
}

extern "C" void kernel_launch(void* const* d_in, const int* in_sizes, int n_in,
                              void* d_out, int out_size, void* d_ws, size_t ws_size,
                              hipStream_t stream) {
    const float* logits = (const float*)d_in[0];
    const int*   labels = (const int*)d_in[1];
    float* out = (float*)d_out;
    float* wsf = (float*)d_ws;                                   // 2048*4 floats = 32 KB
    unsigned int* cnt = (unsigned int*)((char*)d_ws + NBLK * 4 * sizeof(float));

    hipMemsetAsync(cnt, 0, sizeof(unsigned int), stream);
    dice_fused<<<NBLK, THREADS, 0, stream>>>(logits, labels, wsf, cnt, out);
}

// Round 10
// 216.628 us; speedup vs baseline: 1.8512x; 1.8512x over previous
//
#include <hip/hip_runtime.h>

constexpr int HW = 1024 * 1024;
constexpr int NB = 16;
constexpr float EPS = 1e-6f;
constexpr int BLOCKS_PER_BATCH = 128;  // 2048 blocks total -> 8 blocks/CU
constexpr int THREADS = 256;
constexpr int NVEC    = HW / 4;                      // 262144 vec4 per batch
constexpr int TPB     = BLOCKS_PER_BATCH * THREADS;  // 32768 threads per batch
constexpr int U       = NVEC / TPB;                  // 8 windows per thread (exact)
constexpr int NBLK    = NB * BLOCKS_PER_BATCH;       // 2048

typedef float f32x4 __attribute__((ext_vector_type(4)));
typedef int   i32x4 __attribute__((ext_vector_type(4)));

// Stage 1: per-block partials -> ws4[gid] = {Sp, Spp, St, Stp}. No atomics.
// nt loads (confirmed +15 µs win in R8 A/B), depth-2 rotating pipeline
// (depth-3 neutral in R7). Fusion via agent-scope fence regressed 185 µs (R9)
// — per-XCD L2 writeback on every release. Keep two kernels.
__global__ __launch_bounds__(THREADS, 8) void dice_partial(
        const float* __restrict__ logits,
        const int*   __restrict__ labels,
        f32x4*       __restrict__ ws4) {
    const int b   = blockIdx.x >> 7;         // / BLOCKS_PER_BATCH
    const int blk = blockIdx.x & 127;        // % BLOCKS_PER_BATCH

    const f32x4* __restrict__ L0 = reinterpret_cast<const f32x4*>(logits + (size_t)b * 2 * HW);
    const f32x4* __restrict__ L1 = reinterpret_cast<const f32x4*>(logits + (size_t)b * 2 * HW + HW);
    const i32x4* __restrict__ LB = reinterpret_cast<const i32x4*>(labels + (size_t)b * HW);

    const int base = blk * THREADS + threadIdx.x;   // [0, 32768)

    f32x4 a[2], c[2];
    i32x4 t[2];
    a[0] = __builtin_nontemporal_load(&L0[base]);
    c[0] = __builtin_nontemporal_load(&L1[base]);
    t[0] = __builtin_nontemporal_load(&LB[base]);
    a[1] = __builtin_nontemporal_load(&L0[base + TPB]);
    c[1] = __builtin_nontemporal_load(&L1[base + TPB]);
    t[1] = __builtin_nontemporal_load(&LB[base + TPB]);

    float sp = 0.f, spp = 0.f, st = 0.f, stp = 0.f;

    #pragma unroll
    for (int u = 0; u < U; ++u) {
        const int cur = u & 1;
        f32x4 an, cn;
        i32x4 tn;
        const bool pf = (u + 2 < U);
        if (pf) {
            const int i = base + (u + 2) * TPB;
            an = __builtin_nontemporal_load(&L0[i]);
            cn = __builtin_nontemporal_load(&L1[i]);
            tn = __builtin_nontemporal_load(&LB[i]);
        }
        #pragma unroll
        for (int k = 0; k < 4; ++k) {
            const float p  = 1.f / (1.f + __expf(a[cur][k] - c[cur][k]));
            const float tf = (float)t[cur][k];
            sp += p; spp = fmaf(p, p, spp); st += tf; stp = fmaf(tf, p, stp);
        }
        if (pf) { a[cur] = an; c[cur] = cn; t[cur] = tn; }
    }

    // wave-64 shuffle reduction
    #pragma unroll
    for (int off = 32; off > 0; off >>= 1) {
        sp  += __shfl_down(sp,  off);
        spp += __shfl_down(spp, off);
        st  += __shfl_down(st,  off);
        stp += __shfl_down(stp, off);
    }

    __shared__ float red[4][4];   // [wave][component]
    const int wave = threadIdx.x >> 6;
    const int lane = threadIdx.x & 63;
    if (lane == 0) {
        red[wave][0] = sp; red[wave][1] = spp; red[wave][2] = st; red[wave][3] = stp;
    }
    __syncthreads();
    if (threadIdx.x == 0) {
        f32x4 r;
        r.x = red[0][0] + red[1][0] + red[2][0] + red[3][0];
        r.y = red[0][1] + red[1][1] + red[2][1] + red[3][1];
        r.z = red[0][2] + red[1][2] + red[2][2] + red[3][2];
        r.w = red[0][3] + red[1][3] + red[2][3] + red[3][3];
        ws4[blockIdx.x] = r;   // plain store, distinct slot per block
    }
}

// Stage 2 (merged): one block, 1024 threads = 16 waves; wave w folds batch w's
// 128 partials and computes its dice term; wave 0 then folds the 16 terms.
__global__ __launch_bounds__(1024) void dice_reduce(
        const f32x4* __restrict__ ws4,
        float*       __restrict__ out) {
    const int wave = threadIdx.x >> 6;   // 0..15 == batch index
    const int lane = threadIdx.x & 63;

    f32x4 v = ws4[wave * BLOCKS_PER_BATCH + lane]
            + ws4[wave * BLOCKS_PER_BATCH + 64 + lane];

    #pragma unroll
    for (int off = 32; off > 0; off >>= 1) {
        v.x += __shfl_down(v.x, off);
        v.y += __shfl_down(v.y, off);
        v.z += __shfl_down(v.z, off);
        v.w += __shfl_down(v.w, off);
    }

    __shared__ float terms[NB];
    if (lane == 0) {
        const float Sp  = v.x;
        const float Spp = v.y;
        const float St  = v.z;
        const float Stp = v.w;
        const float N = (float)HW;

        const float num1 = 2.f * Stp;
        const float den1 = Spp + St;
        const float num0 = 2.f * (N - St - Sp + Stp);
        const float den0 = (N - 2.f * Sp + Spp) + (N - St);

        terms[wave] = num0 / (den0 + EPS) + num1 / (den1 + EPS);
    }
    __syncthreads();
    if (threadIdx.x == 0) {
        float s = 0.f;
        #pragma unroll
        for (int i = 0; i < NB; ++i) s += terms[i];
        out[0] = 1.f - s / 32.f;
    }
}

extern "C" void kernel_launch(void* const* d_in, const int* in_sizes, int n_in,
                              void* d_out, int out_size, void* d_ws, size_t ws_size,
                              hipStream_t stream) {
    const float* logits = (const float*)d_in[0];
    const int*   labels = (const int*)d_in[1];
    float* out = (float*)d_out;
    f32x4* ws4 = (f32x4*)d_ws;                       // 2048 vec4 = 32 KB

    dice_partial<<<NBLK, THREADS, 0, stream>>>(logits, labels, ws4);
    dice_reduce<<<1, 1024, 0, stream>>>(ws4, out);
}